// Round 3
// baseline (2980.020 us; speedup 1.0000x reference)
//
#include <hip/hip_runtime.h>
#include <stdint.h>

// ---------------------------------------------------------------------------
#define LSEQ 768
#define DM   256
#define NH   8
#define DK   32
#define DFF  1024
#define NLAYER 8
#define NDD  1535
// ---------------------------------------------------------------------------

typedef __attribute__((ext_vector_type(8))) short  bf16x8;
typedef __attribute__((ext_vector_type(4))) float  f32x4;

__device__ __forceinline__ unsigned short f2bf(float f) {
  unsigned u = __float_as_uint(f);
  u += 0x7fffu + ((u >> 16) & 1u);       // RNE
  return (unsigned short)(u >> 16);
}

// ---------------------------------------------------------------------------
// Device-scope grid barrier: monotonic counter, one arrival per block.
// Caller passes tgt = generation*gridDim.x. Release: __threadfence before
// signal (flushes this XCD's L2); acquire: __threadfence after spin.
__device__ __forceinline__ void grid_bar(unsigned int* bar, unsigned int tgt) {
  __syncthreads();
  if (threadIdx.x == 0) {
    __threadfence();
    __hip_atomic_fetch_add(bar, 1u, __ATOMIC_RELAXED, __HIP_MEMORY_SCOPE_AGENT);
    while (__hip_atomic_load(bar, __ATOMIC_RELAXED, __HIP_MEMORY_SCOPE_AGENT) < tgt) {
      __builtin_amdgcn_s_sleep(2);
    }
    __threadfence();
  }
  __syncthreads();
}

// ---------------------------------------------------------------------------
// GEMM tile device fn: 64x64 tile, BK=32, register-prefetch double-buffered.
// LDS carve (from smc): As 2x32x68 f32 @0 (17408), Bs @17408 (17408),
// stat @34816 (512), red @35328 (2048) -> 37376 total.
template <int LN, int GELU, int RES, int GATHER, int ATOMIC>
__device__ void gemm_tile(const float* A, int lda,
                          const float* gsrc, const int* gather,
                          const float* B, const float* bias, float* C,
                          const float* res, const float* lns, const float* lnb,
                          int M, int K, int N, int m0, int n0, char* smc) {
  float (*As)[32][68] = (float (*)[32][68])smc;
  float (*Bs)[32][68] = (float (*)[32][68])(smc + 17408);
  float (*stat)[2]    = (float (*)[2])(smc + 34816);
  float (*red)[8]     = (float (*)[8])(smc + 35328);

  int t = threadIdx.x;
  int arow = t >> 2, akq = (t & 3) * 8;
  int mg = m0 + arow;
  int mgc = mg < M ? mg : M - 1;
  const float* Ar = GATHER ? (gsrc + (size_t)gather[mgc] * K)
                           : (A + (size_t)mgc * lda);
  float mean = 0.f, rstd = 0.f;
  if (LN) {
    int lq = t & 3;
    float s = 0.f, s2 = 0.f;
    const float* p = Ar + lq * 64;
    #pragma unroll
    for (int c = 0; c < 64; c += 4) {
      float4 v = *(const float4*)(p + c);
      s  += v.x + v.y + v.z + v.w;
      s2 += v.x * v.x + v.y * v.y + v.z * v.z + v.w * v.w;
    }
    red[arow][lq] = s; red[arow][lq + 4] = s2;
    __syncthreads();
    if (lq == 0) {
      float sm = red[arow][0] + red[arow][1] + red[arow][2] + red[arow][3];
      float sq = red[arow][4] + red[arow][5] + red[arow][6] + red[arow][7];
      float m = sm * (1.f / 256.f);
      float v = sq * (1.f / 256.f) - m * m;
      stat[arow][0] = m;
      stat[arow][1] = rsqrtf(v + 1e-5f);
    }
    __syncthreads();
    mean = stat[arow][0]; rstd = stat[arow][1];
  }

  int bkr = t >> 3, bn8 = (t & 7) * 8;
  int ty = t >> 4, tx = t & 15;
  float acc[4][4] = {};
  int nk = K >> 5;
  float4 a0, a1, b0, b1;

  {
    a0 = *(const float4*)(Ar + akq);
    a1 = *(const float4*)(Ar + akq + 4);
    if (LN) {
      float4 ls0 = *(const float4*)(lns + akq), ls1 = *(const float4*)(lns + akq + 4);
      float4 lb0 = *(const float4*)(lnb + akq), lb1 = *(const float4*)(lnb + akq + 4);
      a0.x=(a0.x-mean)*rstd*ls0.x+lb0.x; a0.y=(a0.y-mean)*rstd*ls0.y+lb0.y;
      a0.z=(a0.z-mean)*rstd*ls0.z+lb0.z; a0.w=(a0.w-mean)*rstd*ls0.w+lb0.w;
      a1.x=(a1.x-mean)*rstd*ls1.x+lb1.x; a1.y=(a1.y-mean)*rstd*ls1.y+lb1.y;
      a1.z=(a1.z-mean)*rstd*ls1.z+lb1.z; a1.w=(a1.w-mean)*rstd*ls1.w+lb1.w;
    }
    b0 = *(const float4*)(B + (size_t)bkr * N + n0 + bn8);
    b1 = *(const float4*)(B + (size_t)bkr * N + n0 + bn8 + 4);
    As[0][akq+0][arow]=a0.x; As[0][akq+1][arow]=a0.y; As[0][akq+2][arow]=a0.z; As[0][akq+3][arow]=a0.w;
    As[0][akq+4][arow]=a1.x; As[0][akq+5][arow]=a1.y; As[0][akq+6][arow]=a1.z; As[0][akq+7][arow]=a1.w;
    *(float4*)&Bs[0][bkr][bn8] = b0;
    *(float4*)&Bs[0][bkr][bn8+4] = b1;
  }
  __syncthreads();

  for (int kt = 0; kt < nk; ++kt) {
    int cur = kt & 1;
    if (kt + 1 < nk) {
      int k0 = (kt + 1) << 5;
      a0 = *(const float4*)(Ar + k0 + akq);
      a1 = *(const float4*)(Ar + k0 + akq + 4);
      if (LN) {
        float4 ls0 = *(const float4*)(lns + k0 + akq), ls1 = *(const float4*)(lns + k0 + akq + 4);
        float4 lb0 = *(const float4*)(lnb + k0 + akq), lb1 = *(const float4*)(lnb + k0 + akq + 4);
        a0.x=(a0.x-mean)*rstd*ls0.x+lb0.x; a0.y=(a0.y-mean)*rstd*ls0.y+lb0.y;
        a0.z=(a0.z-mean)*rstd*ls0.z+lb0.z; a0.w=(a0.w-mean)*rstd*ls0.w+lb0.w;
        a1.x=(a1.x-mean)*rstd*ls1.x+lb1.x; a1.y=(a1.y-mean)*rstd*ls1.y+lb1.y;
        a1.z=(a1.z-mean)*rstd*ls1.z+lb1.z; a1.w=(a1.w-mean)*rstd*ls1.w+lb1.w;
      }
      b0 = *(const float4*)(B + (size_t)(k0 + bkr) * N + n0 + bn8);
      b1 = *(const float4*)(B + (size_t)(k0 + bkr) * N + n0 + bn8 + 4);
    }
    #pragma unroll
    for (int kk = 0; kk < 32; ++kk) {
      float4 a = *(float4*)&As[cur][kk][ty * 4];
      float4 b = *(float4*)&Bs[cur][kk][tx * 4];
      acc[0][0]=fmaf(a.x,b.x,acc[0][0]); acc[0][1]=fmaf(a.x,b.y,acc[0][1]);
      acc[0][2]=fmaf(a.x,b.z,acc[0][2]); acc[0][3]=fmaf(a.x,b.w,acc[0][3]);
      acc[1][0]=fmaf(a.y,b.x,acc[1][0]); acc[1][1]=fmaf(a.y,b.y,acc[1][1]);
      acc[1][2]=fmaf(a.y,b.z,acc[1][2]); acc[1][3]=fmaf(a.y,b.w,acc[1][3]);
      acc[2][0]=fmaf(a.z,b.x,acc[2][0]); acc[2][1]=fmaf(a.z,b.y,acc[2][1]);
      acc[2][2]=fmaf(a.z,b.z,acc[2][2]); acc[2][3]=fmaf(a.z,b.w,acc[2][3]);
      acc[3][0]=fmaf(a.w,b.x,acc[3][0]); acc[3][1]=fmaf(a.w,b.y,acc[3][1]);
      acc[3][2]=fmaf(a.w,b.z,acc[3][2]); acc[3][3]=fmaf(a.w,b.w,acc[3][3]);
    }
    if (kt + 1 < nk) {
      int nxt = cur ^ 1;
      As[nxt][akq+0][arow]=a0.x; As[nxt][akq+1][arow]=a0.y; As[nxt][akq+2][arow]=a0.z; As[nxt][akq+3][arow]=a0.w;
      As[nxt][akq+4][arow]=a1.x; As[nxt][akq+5][arow]=a1.y; As[nxt][akq+6][arow]=a1.z; As[nxt][akq+7][arow]=a1.w;
      *(float4*)&Bs[nxt][bkr][bn8] = b0;
      *(float4*)&Bs[nxt][bkr][bn8+4] = b1;
    }
    __syncthreads();
  }

  #pragma unroll
  for (int u = 0; u < 4; ++u) {
    int m = m0 + ty * 4 + u;
    if (m < M) {
      #pragma unroll
      for (int vv = 0; vv < 4; ++vv) {
        int n = n0 + tx * 4 + vv;
        float val = acc[u][vv];
        if (bias) val += bias[n];
        if (GELU) val = 0.5f * val * (1.f + erff(val * 0.70710678118654752f));
        if (RES) val += res[(size_t)m * N + n];
        if (ATOMIC) atomicAdd(&C[(size_t)m * N + n], val);
        else        C[(size_t)m * N + n] = val;
      }
    }
  }
}

// ---------------------------------------------------------------------------
// Attention task: 16 query rows x 1 head. LDS carve (from smc):
// S [16][776] @0 (49664), red [16][16] @49664 (1024), mrow @50688 (64),
// linv @50752 (64), pr [2304] @50816 (9216) -> 60032 total.
__device__ void attn_task(const float* q, const float* k, const float* v,
                          const float* abias, float* o, int i0, int h, char* smc) {
  float* S = (float*)smc;
  float (*red)[16] = (float (*)[16])(smc + 49664);
  float* mrow = (float*)(smc + 50688);
  float* linv = (float*)(smc + 50752);
  float* pr   = (float*)(smc + 50816);

  int hc = h * DK;
  int t = threadIdx.x;
  int ti = t >> 4, tj = t & 15;

  float qr[32];
  {
    const float* qp = q + (size_t)(i0 + ti) * DM + hc;
    const float inv = 0.17677669529663687f;   // 1/sqrt(32)
    #pragma unroll
    for (int c = 0; c < 32; c += 4) {
      float4 v4 = *(const float4*)(qp + c);
      qr[c+0] = v4.x * inv; qr[c+1] = v4.y * inv;
      qr[c+2] = v4.z * inv; qr[c+3] = v4.w * inv;
    }
  }

  float mx = -1e30f;
  for (int jc = 0; jc < 48; ++jc) {
    int j = jc * 16 + tj;
    const float* kr = k + (size_t)j * DM + hc;
    float acc = 0.f;
    #pragma unroll
    for (int c = 0; c < 32; c += 4) {
      float4 kv = *(const float4*)(kr + c);
      acc = fmaf(qr[c+0], kv.x, acc);
      acc = fmaf(qr[c+1], kv.y, acc);
      acc = fmaf(qr[c+2], kv.z, acc);
      acc = fmaf(qr[c+3], kv.w, acc);
    }
    acc += abias[(size_t)(i0 + ti - j + 767) * 8 + h];
    S[ti * 776 + j] = acc;
    mx = fmaxf(mx, acc);
  }
  red[ti][tj] = mx;
  __syncthreads();
  if (tj == 0) {
    float m2 = red[ti][0];
    #pragma unroll
    for (int u = 1; u < 16; ++u) m2 = fmaxf(m2, red[ti][u]);
    mrow[ti] = m2;
  }
  __syncthreads();
  float m2 = mrow[ti];
  float sum = 0.f;
  for (int jc = 0; jc < 48; ++jc) {
    int j = jc * 16 + tj;
    float e = __expf(S[ti * 776 + j] - m2);
    S[ti * 776 + j] = e;
    sum += e;
  }
  red[ti][tj] = sum;
  __syncthreads();
  if (tj == 0) {
    float s2 = 0.f;
    #pragma unroll
    for (int u = 0; u < 16; ++u) s2 += red[ti][u];
    linv[ti] = 1.f / s2;
  }
  __syncthreads();

  {
    int wv = t >> 6, l = t & 63;
    int c4 = (l & 7) * 4;
    int ib = l >> 3;
    float a00=0,a01=0,a02=0,a03=0, a10=0,a11=0,a12=0,a13=0;
    const float* vp = v + hc + c4;
    int jbeg = wv * 192;
    for (int j = jbeg; j < jbeg + 192; j += 4) {
      float4 s0 = *(float4*)&S[ib * 776 + j];
      float4 s1 = *(float4*)&S[(ib + 8) * 776 + j];
      const float* vj = vp + (size_t)j * DM;
      float4 v0 = *(const float4*)(vj);
      float4 v1 = *(const float4*)(vj + DM);
      float4 v2 = *(const float4*)(vj + 2 * DM);
      float4 v3 = *(const float4*)(vj + 3 * DM);
      a00=fmaf(s0.x,v0.x,a00); a01=fmaf(s0.x,v0.y,a01); a02=fmaf(s0.x,v0.z,a02); a03=fmaf(s0.x,v0.w,a03);
      a10=fmaf(s1.x,v0.x,a10); a11=fmaf(s1.x,v0.y,a11); a12=fmaf(s1.x,v0.z,a12); a13=fmaf(s1.x,v0.w,a13);
      a00=fmaf(s0.y,v1.x,a00); a01=fmaf(s0.y,v1.y,a01); a02=fmaf(s0.y,v1.z,a02); a03=fmaf(s0.y,v1.w,a03);
      a10=fmaf(s1.y,v1.x,a10); a11=fmaf(s1.y,v1.y,a11); a12=fmaf(s1.y,v1.z,a12); a13=fmaf(s1.y,v1.w,a13);
      a00=fmaf(s0.z,v2.x,a00); a01=fmaf(s0.z,v2.y,a01); a02=fmaf(s0.z,v2.z,a02); a03=fmaf(s0.z,v2.w,a03);
      a10=fmaf(s1.z,v2.x,a10); a11=fmaf(s1.z,v2.y,a11); a12=fmaf(s1.z,v2.z,a12); a13=fmaf(s1.z,v2.w,a13);
      a00=fmaf(s0.w,v3.x,a00); a01=fmaf(s0.w,v3.y,a01); a02=fmaf(s0.w,v3.z,a02); a03=fmaf(s0.w,v3.w,a03);
      a10=fmaf(s1.w,v3.x,a10); a11=fmaf(s1.w,v3.y,a11); a12=fmaf(s1.w,v3.z,a12); a13=fmaf(s1.w,v3.w,a13);
    }
    pr[(ib * 4 + wv) * 36 + c4 + 0] = a00;
    pr[(ib * 4 + wv) * 36 + c4 + 1] = a01;
    pr[(ib * 4 + wv) * 36 + c4 + 2] = a02;
    pr[(ib * 4 + wv) * 36 + c4 + 3] = a03;
    pr[((ib + 8) * 4 + wv) * 36 + c4 + 0] = a10;
    pr[((ib + 8) * 4 + wv) * 36 + c4 + 1] = a11;
    pr[((ib + 8) * 4 + wv) * 36 + c4 + 2] = a12;
    pr[((ib + 8) * 4 + wv) * 36 + c4 + 3] = a13;
  }
  __syncthreads();
  #pragma unroll
  for (int u = 0; u < 2; ++u) {
    int idx = t * 2 + u;
    int i = idx >> 5, c = idx & 31;
    float s = pr[(i*4+0)*36 + c] + pr[(i*4+1)*36 + c]
            + pr[(i*4+2)*36 + c] + pr[(i*4+3)*36 + c];
    o[(size_t)(i0 + i) * DM + hc + c] = s * linv[i];
  }
}

// ---------------------------------------------------------------------------
// Persistent megakernel: prep + RB + 8 transformer layers + pair projection.
// grid = 256 blocks (1/CU), 41 grid barriers. NO early returns anywhere.
__global__ __launch_bounds__(256, 1) void k_stack(
    const int* __restrict__ seq, const float* __restrict__ tok_emb,
    const float* __restrict__ rp_emb,
    const float* __restrict__ wq, const float* __restrict__ wk,
    const float* __restrict__ wv, const float* __restrict__ wo_,
    const float* __restrict__ ln1_s, const float* __restrict__ ln1_b,
    const float* __restrict__ ln2_s, const float* __restrict__ ln2_b,
    const float* __restrict__ ffn_w1, const float* __restrict__ ffn_b1,
    const float* __restrict__ ffn_w2, const float* __restrict__ ffn_b2,
    const float* __restrict__ lnf_s, const float* __restrict__ lnf_b,
    const float* __restrict__ pair_q_w, const float* __restrict__ pair_q_b,
    const float* __restrict__ pair_k_w, const float* __restrict__ pair_k_b,
    const float* __restrict__ pair_rp, const float* __restrict__ cls_w1,
    const float* __restrict__ cls_b1,
    float* x, float* q, float* k, float* v, float* o, float* f1,
    float* pq, float* pk, float* RB, unsigned short* W1p,
    int* lut, float* abias, unsigned int* bar) {
  __shared__ __align__(16) char sm[60032];
  int bid = blockIdx.x, t = threadIdx.x;
  unsigned int gen = 0;

  // ---- P0: prep (LUT+abias / embed / W1p pack) ----
  if (bid < 6) {
    int dd = bid * 256 + t;
    if (dd < NDD) {
      int rel = dd - 767;
      int ret = rel < 0 ? 32 : 0;
      int arp = rel < 0 ? -rel : rel;
      int bk;
      if (arp < 16) {
        bk = ret + arp;
      } else {
        const float lr = 2.772588722239781f;   // float(np.log(16))
        float val = logf((float)arp * 0.0625f) / lr * 16.0f;
        int vi = 16 + (int)val;
        bk = ret + (vi < 31 ? vi : 31);
      }
      lut[dd] = bk;
      #pragma unroll
      for (int h = 0; h < NH; ++h) abias[dd * 8 + h] = rp_emb[bk * 8 + h];
    }
  }
  if (t < 192) {   // embed: 3 rows per block
    int row = bid * 3 + (t >> 6), c = (t & 63) * 4;
    *(float4*)(x + (size_t)row * DM + c) =
        *(const float4*)(tok_emb + (size_t)seq[row] * DM + c);
  }
  {  // W1p fragment-order pack: 1 element per thread
    int id = bid * 256 + t;
    int e = id & 7, lane = (id >> 3) & 63, g = (id >> 9) & 15, kc = id >> 13;
    W1p[id] = f2bf(cls_w1[(size_t)(kc * 32 + (lane >> 4) * 8 + e) * 256
                          + g * 16 + (lane & 15)]);
  }
  grid_bar(bar, (++gen) * 256u);

  // ---- P1: RB gemm (96 tiles) + qkv layer 0 (144 tiles) ----
  if (bid < 96) {
    int m0 = (bid % 24) * 64, n0 = (bid / 24) * 64;
    gemm_tile<0,0,0,1,0>(nullptr, 256, pair_rp, lut, cls_w1, cls_b1, RB,
                         nullptr, nullptr, nullptr, NDD, 256, 256, m0, n0, sm);
  } else if (bid < 240) {
    int u = bid - 96;
    int n0g = (u % 12) * 64, m0 = (u / 12) * 64;
    int bi = n0g >> 8, n0 = n0g & 255;
    const float* B = bi == 0 ? wq : (bi == 1 ? wk : wv);
    float* C = bi == 0 ? q : (bi == 1 ? k : v);
    gemm_tile<1,0,0,0,0>(x, 256, nullptr, nullptr, B, nullptr, C, nullptr,
                         ln1_s, ln1_b, LSEQ, 256, 256, m0, n0, sm);
  }
  grid_bar(bar, (++gen) * 256u);

  for (int l = 0; l < NLAYER; ++l) {
    const float* wo_l  = wo_ + (size_t)l * DM * DM;
    const float* ln2sl = ln2_s + l * DM;
    const float* ln2bl = ln2_b + l * DM;
    const float* fw1_l = ffn_w1 + (size_t)l * DM * DFF;
    const float* fb1_l = ffn_b1 + (size_t)l * DFF;
    const float* fw2_l = ffn_w2 + (size_t)l * DFF * DM;
    const float* fb2_l = ffn_b2 + (size_t)l * DM;

    // attn: 384 tasks (16 rows x head)
    for (int task = bid; task < 384; task += 256)
      attn_task(q, k, v, abias, o, (task % 48) * 16, task / 48, sm);
    grid_bar(bar, (++gen) * 256u);

    // wo: x += o @ Wo   (48 tiles)
    if (bid < 48) {
      int m0 = (bid >> 2) * 64, n0 = (bid & 3) * 64;
      gemm_tile<0,0,1,0,0>(o, 256, nullptr, nullptr, wo_l, nullptr, x, x,
                           nullptr, nullptr, LSEQ, 256, 256, m0, n0, sm);
    }
    grid_bar(bar, (++gen) * 256u);

    // ffn1: f1 = gelu(LN2(x) @ fw1 + fb1)   (192 tiles)
    if (bid < 192) {
      int m0 = (bid >> 4) * 64, n0 = (bid & 15) * 64;
      gemm_tile<1,1,0,0,0>(x, 256, nullptr, nullptr, fw1_l, fb1_l, f1,
                           nullptr, ln2sl, ln2bl, LSEQ, 256, 1024, m0, n0, sm);
    }
    grid_bar(bar, (++gen) * 256u);

    // ffn2 split-K(4): x += f1 @ fw2 (+fb2 once), atomicAdd epilogue (192 tiles)
    if (bid < 192) {
      int kc = bid / 48, v2 = bid % 48;
      int m0 = (v2 >> 2) * 64, n0 = (v2 & 3) * 64;
      gemm_tile<0,0,0,0,1>(f1 + kc * 256, 1024, nullptr, nullptr,
                           fw2_l + (size_t)(kc * 256) * 256,
                           kc == 0 ? fb2_l : nullptr, x, nullptr,
                           nullptr, nullptr, LSEQ, 256, 256, m0, n0, sm);
    }
    grid_bar(bar, (++gen) * 256u);

    if (l < NLAYER - 1) {
      // next layer qkv (144 tiles)
      const float* wq_n = wq + (size_t)(l + 1) * DM * DM;
      const float* wk_n = wk + (size_t)(l + 1) * DM * DM;
      const float* wv_n = wv + (size_t)(l + 1) * DM * DM;
      const float* ln1sl = ln1_s + (l + 1) * DM;
      const float* ln1bl = ln1_b + (l + 1) * DM;
      if (bid < 144) {
        int n0g = (bid % 12) * 64, m0 = (bid / 12) * 64;
        int bi = n0g >> 8, n0 = n0g & 255;
        const float* B = bi == 0 ? wq_n : (bi == 1 ? wk_n : wv_n);
        float* C = bi == 0 ? q : (bi == 1 ? k : v);
        gemm_tile<1,0,0,0,0>(x, 256, nullptr, nullptr, B, nullptr, C, nullptr,
                             ln1sl, ln1bl, LSEQ, 256, 256, m0, n0, sm);
      }
      grid_bar(bar, (++gen) * 256u);
    } else {
      // pair projection: pq/pk = LNf(x) @ pair_{q,k}_w + bias  (96 tiles)
      if (bid < 96) {
        int n0g = (bid % 8) * 64, m0 = (bid / 8) * 64;
        int bi = n0g >> 8, n0 = n0g & 255;
        const float* B = bi ? pair_k_w : pair_q_w;
        const float* bb = bi ? pair_k_b : pair_q_b;
        float* C = bi ? pk : pq;
        gemm_tile<1,0,0,0,0>(x, 256, nullptr, nullptr, B, bb, C, nullptr,
                             lnf_s, lnf_b, LSEQ, 256, 256, m0, n0, sm);
      }
      // kernel end = implicit sync before k_pair dispatch
    }
  }
}

// ---------------------------------------------------------------------------
// Fused pair head (unchanged from round 2). Register A-gen, global
// fragment-order B, no K-loop barriers.
#define PAIR_SMEM (36400 + 33792)

__global__ __launch_bounds__(256, 2) void k_pair(
    const float* __restrict__ pq, const float* __restrict__ pk,
    const unsigned short* __restrict__ W1p, const float* __restrict__ RB,
    const float* __restrict__ w2, const float* __restrict__ b2,
    float* __restrict__ out) {
  extern __shared__ char smem[];
  float* RB_s = (float*)smem;
  float* part = (float*)(smem + 36400);

  int t = threadIdx.x;
  int j0 = blockIdx.x * 32;
  int i0 = blockIdx.y * 4;
  int w = t >> 6, l = t & 63;
  int q4 = l >> 4, l15 = l & 15;
  int mwv = w & 1, nwv = w >> 1;

  {
    int ddmin = i0 - j0 + 736;
    for (int idx = t; idx < 35 * 64; idx += 256) {
      int lc = idx >> 6, c4 = (idx & 63) * 4;
      *(float4*)(RB_s + lc * 260 + c4) =
          *(const float4*)(RB + (size_t)(ddmin + lc) * 256 + c4);
    }
  }

  const float* q0p = pq + (size_t)(i0 + mwv * 2    ) * DM;
  const float* q1p = pq + (size_t)(i0 + mwv * 2 + 1) * DM;
  const float* k0p = pk + (size_t)(j0 + l15        ) * DM;
  const float* k1p = pk + (size_t)(j0 + 16 + l15   ) * DM;
  const unsigned short* Bp = W1p + (size_t)(nwv * 8) * 512 + (size_t)l * 8;

  f32x4 acc[4][8];
  #pragma unroll
  for (int a = 0; a < 4; ++a)
    #pragma unroll
    for (int b = 0; b < 8; ++b) acc[a][b] = (f32x4){0.f, 0.f, 0.f, 0.f};

  #pragma unroll 2
  for (int kc = 0; kc < 8; ++kc) {
    int c = kc * 32 + q4 * 8;
    float4 qa0 = *(const float4*)(q0p + c), qa1 = *(const float4*)(q0p + c + 4);
    float4 qb0 = *(const float4*)(q1p + c), qb1 = *(const float4*)(q1p + c + 4);
    float4 ka0 = *(const float4*)(k0p + c), ka1 = *(const float4*)(k0p + c + 4);
    float4 kb0 = *(const float4*)(k1p + c), kb1 = *(const float4*)(k1p + c + 4);

    bf16x8 bfv[8];
    const unsigned short* bb = Bp + (size_t)kc * 8192;
    #pragma unroll
    for (int nt = 0; nt < 8; ++nt)
      bfv[nt] = *(const bf16x8*)(bb + nt * 512);

    bf16x8 af[4];
    af[0][0]=(short)f2bf(qa0.x*ka0.x); af[0][1]=(short)f2bf(qa0.y*ka0.y);
    af[0][2]=(short)f2bf(qa0.z*ka0.z); af[0][3]=(short)f2bf(qa0.w*ka0.w);
    af[0][4]=(short)f2bf(qa1.x*ka1.x); af[0][5]=(short)f2bf(qa1.y*ka1.y);
    af[0][6]=(short)f2bf(qa1.z*ka1.z); af[0][7]=(short)f2bf(qa1.w*ka1.w);
    af[1][0]=(short)f2bf(qa0.x*kb0.x); af[1][1]=(short)f2bf(qa0.y*kb0.y);
    af[1][2]=(short)f2bf(qa0.z*kb0.z); af[1][3]=(short)f2bf(qa0.w*kb0.w);
    af[1][4]=(short)f2bf(qa1.x*kb1.x); af[1][5]=(short)f2bf(qa1.y*kb1.y);
    af[1][6]=(short)f2bf(qa1.z*kb1.z); af[1][7]=(short)f2bf(qa1.w*kb1.w);
    af[2][0]=(short)f2bf(qb0.x*ka0.x); af[2][1]=(short)f2bf(qb0.y*ka0.y);
    af[2][2]=(short)f2bf(qb0.z*ka0.z); af[2][3]=(short)f2bf(qb0.w*ka0.w);
    af[2][4]=(short)f2bf(qb1.x*ka1.x); af[2][5]=(short)f2bf(qb1.y*ka1.y);
    af[2][6]=(short)f2bf(qb1.z*ka1.z); af[2][7]=(short)f2bf(qb1.w*ka1.w);
    af[3][0]=(short)f2bf(qb0.x*kb0.x); af[3][1]=(short)f2bf(qb0.y*kb0.y);
    af[3][2]=(short)f2bf(qb0.z*kb0.z); af[3][3]=(short)f2bf(qb0.w*kb0.w);
    af[3][4]=(short)f2bf(qb1.x*kb1.x); af[3][5]=(short)f2bf(qb1.y*kb1.y);
    af[3][6]=(short)f2bf(qb1.z*kb1.z); af[3][7]=(short)f2bf(qb1.w*kb1.w);

    #pragma unroll
    for (int mt = 0; mt < 4; ++mt)
      #pragma unroll
      for (int nt = 0; nt < 8; ++nt)
        acc[mt][nt] = __builtin_amdgcn_mfma_f32_16x16x32_bf16(af[mt], bfv[nt], acc[mt][nt], 0, 0, 0);
  }

  __syncthreads();

  float w20[8], w21[8];
  #pragma unroll
  for (int nt = 0; nt < 8; ++nt) {
    int n = nwv * 128 + nt * 16 + l15;
    w20[nt] = w2[n * 2];
    w21[nt] = w2[n * 2 + 1];
  }
  #pragma unroll
  for (int mt = 0; mt < 4; ++mt) {
    #pragma unroll
    for (int reg = 0; reg < 4; ++reg) {
      int r = mwv * 64 + mt * 16 + q4 * 4 + reg;
      int lc = (r >> 5) - (r & 31) + 31;
      float o0 = 0.f, o1 = 0.f;
      #pragma unroll
      for (int nt = 0; nt < 8; ++nt) {
        int n = nwv * 128 + nt * 16 + l15;
        float T = acc[mt][nt][reg] + RB_s[lc * 260 + n];
        T = fmaxf(T, 0.f);
        o0 = fmaf(T, w20[nt], o0);
        o1 = fmaf(T, w21[nt], o1);
      }
      part[0 * 4224 + r * 33 + nwv * 16 + l15] = o0;
      part[1 * 4224 + r * 33 + nwv * 16 + l15] = o1;
    }
  }
  __syncthreads();
  {
    int r = t >> 1, oo = t & 1;
    float s = 0.f;
    #pragma unroll
    for (int c = 0; c < 32; ++c) s += part[oo * 4224 + r * 33 + c];
    out[((size_t)(i0 + (r >> 5)) * LSEQ + (j0 + (r & 31))) * 2 + oo] = s + b2[oo];
  }
}

// ---------------------------------------------------------------------------
extern "C" void kernel_launch(void* const* d_in, const int* in_sizes, int n_in,
                              void* d_out, int out_size, void* d_ws, size_t ws_size,
                              hipStream_t stream) {
  const int*   seq      = (const int*)  d_in[0];
  const float* tok_emb  = (const float*)d_in[1];
  const float* rp_emb   = (const float*)d_in[2];
  const float* wq       = (const float*)d_in[3];
  const float* wk       = (const float*)d_in[4];
  const float* wv       = (const float*)d_in[5];
  const float* wo       = (const float*)d_in[6];
  const float* ln1_s    = (const float*)d_in[7];
  const float* ln1_b    = (const float*)d_in[8];
  const float* ln2_s    = (const float*)d_in[9];
  const float* ln2_b    = (const float*)d_in[10];
  const float* ffn_w1   = (const float*)d_in[11];
  const float* ffn_b1   = (const float*)d_in[12];
  const float* ffn_w2   = (const float*)d_in[13];
  const float* ffn_b2   = (const float*)d_in[14];
  const float* lnf_s    = (const float*)d_in[15];
  const float* lnf_b    = (const float*)d_in[16];
  const float* pair_q_w = (const float*)d_in[17];
  const float* pair_q_b = (const float*)d_in[18];
  const float* pair_k_w = (const float*)d_in[19];
  const float* pair_k_b = (const float*)d_in[20];
  const float* pair_rp  = (const float*)d_in[21];
  const float* cls_w1   = (const float*)d_in[22];
  const float* cls_b1   = (const float*)d_in[23];
  const float* cls_w2   = (const float*)d_in[24];
  const float* cls_b2   = (const float*)d_in[25];
  float* out = (float*)d_out;

  char* ws = (char*)d_ws;
  float* x   = (float*)(ws + 0);
  float* q   = (float*)(ws + 786432);
  float* k   = (float*)(ws + 1572864);
  float* v   = (float*)(ws + 2359296);
  float* o   = (float*)(ws + 3145728);
  float* f1  = (float*)(ws + 3932160);
  float* pq  = (float*)(ws + 7077888);
  float* pk  = (float*)(ws + 7864320);
  float* RB  = (float*)(ws + 8650752);
  unsigned short* W1p = (unsigned short*)(ws + 10223616);
  int*   lut   = (int*)  (ws + 10354688);
  float* abias = (float*)(ws + 10360832);
  unsigned int* bar = (unsigned int*)(ws + 10410240);

  (void)in_sizes; (void)n_in; (void)out_size; (void)ws_size;

  hipFuncSetAttribute(reinterpret_cast<const void*>(k_pair),
                      hipFuncAttributeMaxDynamicSharedMemorySize, PAIR_SMEM);

  hipMemsetAsync((void*)bar, 0, 256, stream);

  k_stack<<<256, 256, 0, stream>>>(
      seq, tok_emb, rp_emb, wq, wk, wv, wo,
      ln1_s, ln1_b, ln2_s, ln2_b, ffn_w1, ffn_b1, ffn_w2, ffn_b2,
      lnf_s, lnf_b, pair_q_w, pair_q_b, pair_k_w, pair_k_b,
      pair_rp, cls_w1, cls_b1,
      x, q, k, v, o, f1, pq, pk, RB, W1p, lut, abias, bar);

  k_pair<<<dim3(24, 192), 256, PAIR_SMEM, stream>>>(pq, pk, W1p, RB, cls_w2, cls_b2, out);
}